// Round 13
// baseline (566.609 us; speedup 1.0000x reference)
//
#include <hip/hip_runtime.h>

// Problem constants (reference: N=50000 nodes, E=800000 edges, D=128, K=3)
#define Nn 50000
#define Ee 800000
#define Dd 128
#define Kk 3
#define TEA 32   // rows per block tile (17.4 KB LDS)
#define NT 256   // threads per block (4 waves)

// LDS bf16 tile row stride (ushorts): 128 + 8 pad
#define LSTR 136
// Per-matrix packed-weight slot: hi[16384] + lo[16384] ushorts
#define WSLOT 32768

// Bucket sort CSR build: bucket = node >> 8 (196 buckets for N=50000)
#define NBUK 196
#define SCH 2048                      // edges per sort block
#define SB ((Ee + SCH - 1) / SCH)     // 391 blocks per direction
#define FCAP 5632                     // csr_final LDS staging capacity

typedef short sh8 __attribute__((ext_vector_type(8)));    // 8 bf16 (4 VGPRs)
typedef float f32x4 __attribute__((ext_vector_type(4)));  // MFMA C/D
typedef unsigned char u8;

// Split fp32 into bf16 hi (truncate) + bf16 lo (residual, truncate).
__device__ __forceinline__ ushort bfsplit(float x, float* rem) {
  const unsigned u = __float_as_uint(x);
  *rem = x - __uint_as_float(u & 0xffff0000u);
  return (ushort)(u >> 16);
}
__device__ __forceinline__ ushort bftrunc(float x) {
  return (ushort)(__float_as_uint(x) >> 16);
}

// ---- fp8 OCP e4m3fn (software, self-consistent pair; x >= 0 after relu) ----
// encode: RNE at 3-bit mantissa; denormals via round(x*512); clip to 448.
__device__ __forceinline__ u8 f32_to_e4m3(float x) {
  x = fminf(x, 448.f);
  if (x < 0.015625f) return (u8)__float2int_rn(x * 512.f);   // denorm/zero
  const unsigned u = __float_as_uint(x);
  const unsigned r = u + 0x7FFFFu + ((u >> 20) & 1u);        // RNE carry-safe
  const unsigned e = (r >> 23) - 120u;                       // 1..15
  return (u8)((e << 3) | ((r >> 20) & 7u));
}
// decode: normal = as_float((b<<20)+0x3C000000); denorm (b<8) = b * 2^-9.
__device__ __forceinline__ float e4m3_to_f32(unsigned b) {
  const float fn = __uint_as_float((b << 20) + 0x3C000000u);
  const float fd = (float)(int)b * 0.001953125f;
  return (b >= 8u) ? fn : fd;
}
// accumulate 4 fp8 bytes packed in a uint into a float4
__device__ __forceinline__ void accq(unsigned u, float4& a) {
  a.x += e4m3_to_f32(u & 255u);
  a.y += e4m3_to_f32((u >> 8) & 255u);
  a.z += e4m3_to_f32((u >> 16) & 255u);
  a.w += e4m3_to_f32(u >> 24);
}
#define DEC16(v, za) { accq((v).x, za[0]); accq((v).y, za[1]); \
                       accq((v).z, za[2]); accq((v).w, za[3]); }

// (MT*16)x128x128 layer on MFMA 16x16x32_bf16, split-bf16 (3 products).
#define MFMA_LAYER(WH, WL, MT)                                                 \
  {                                                                            \
    _Pragma("unroll")                                                          \
    for (int c = 0; c < 4; ++c) {                                              \
      const sh8 bh0 = *(const sh8*)((WH) + (((nt0    ) * 4 + c) * 64 + lane) * 8); \
      const sh8 bh1 = *(const sh8*)((WH) + (((nt0 + 1) * 4 + c) * 64 + lane) * 8); \
      const sh8 bl0 = *(const sh8*)((WL) + (((nt0    ) * 4 + c) * 64 + lane) * 8); \
      const sh8 bl1 = *(const sh8*)((WL) + (((nt0 + 1) * 4 + c) * 64 + lane) * 8); \
      _Pragma("unroll")                                                        \
      for (int mt = 0; mt < (MT); ++mt) {                                      \
        const int aoff = (mt * 16 + l15) * LSTR + c * 32 + q8 * 8;             \
        const sh8 ah = *(const sh8*)(Sh + aoff);                               \
        const sh8 al = *(const sh8*)(Sl + aoff);                               \
        acc[mt][0] = __builtin_amdgcn_mfma_f32_16x16x32_bf16(ah, bh0, acc[mt][0], 0, 0, 0); \
        acc[mt][1] = __builtin_amdgcn_mfma_f32_16x16x32_bf16(ah, bh1, acc[mt][1], 0, 0, 0); \
        acc[mt][0] = __builtin_amdgcn_mfma_f32_16x16x32_bf16(al, bh0, acc[mt][0], 0, 0, 0); \
        acc[mt][1] = __builtin_amdgcn_mfma_f32_16x16x32_bf16(al, bh1, acc[mt][1], 0, 0, 0); \
        acc[mt][0] = __builtin_amdgcn_mfma_f32_16x16x32_bf16(ah, bl0, acc[mt][0], 0, 0, 0); \
        acc[mt][1] = __builtin_amdgcn_mfma_f32_16x16x32_bf16(ah, bl1, acc[mt][1], 0, 0, 0); \
      }                                                                        \
    }                                                                          \
  }

#define ZERO_ACC(MT)                                             \
  {                                                              \
    _Pragma("unroll")                                            \
    for (int mt = 0; mt < (MT); ++mt)                            \
      _Pragma("unroll")                                          \
      for (int nl = 0; nl < 2; ++nl) {                           \
        acc[mt][nl][0] = 0.f; acc[mt][nl][1] = 0.f;              \
        acc[mt][nl][2] = 0.f; acc[mt][nl][3] = 0.f;              \
      }                                                          \
  }

// hidden = relu(acc + b1) -> split hi/lo back into LDS (C layout -> A layout)
#define HIDDEN_TO_LDS(B1ptr, MT)                                 \
  {                                                              \
    const float b1a = (B1ptr)[w32 + l15];                        \
    const float b1b = (B1ptr)[w32 + 16 + l15];                   \
    _Pragma("unroll")                                            \
    for (int mt = 0; mt < (MT); ++mt)                            \
      _Pragma("unroll")                                          \
      for (int nl = 0; nl < 2; ++nl) {                           \
        const int col = w32 + nl * 16 + l15;                     \
        const float bb = nl ? b1b : b1a;                         \
        _Pragma("unroll")                                        \
        for (int rg = 0; rg < 4; ++rg) {                         \
          const int row = mt * 16 + q8 * 4 + rg;                 \
          const float h = fmaxf(acc[mt][nl][rg] + bb, 0.f);      \
          float rm;                                              \
          const ushort hh = bfsplit(h, &rm);                     \
          const int off = row * LSTR + col;                      \
          Sh[off] = hh;                                          \
          Sl[off] = bftrunc(rm);                                 \
        }                                                        \
      }                                                          \
  }

// stc (C-layout f32, bias included, signed) -> split into LDS A-layout
#define STC_TO_LDS(MT)                                           \
  {                                                              \
    _Pragma("unroll")                                            \
    for (int mt = 0; mt < (MT); ++mt)                            \
      _Pragma("unroll")                                          \
      for (int nl = 0; nl < 2; ++nl) {                           \
        const int col = w32 + nl * 16 + l15;                     \
        _Pragma("unroll")                                        \
        for (int rg = 0; rg < 4; ++rg) {                         \
          const int row = mt * 16 + q8 * 4 + rg;                 \
          float rm;                                              \
          const ushort hh = bfsplit(stc[mt][nl][rg], &rm);       \
          const int off = row * LSTR + col;                      \
          Sh[off] = hh;                                          \
          Sl[off] = bftrunc(rm);                                 \
        }                                                        \
      }                                                          \
  }

// stage rows [row0, row0+nrow) of row-major f32 X (stride Dd) into Sh/Sl split
#define STAGE_ROWS(Xptr)                                                       \
  {                                                                            \
    _Pragma("unroll")                                                          \
    for (int it = 0; it < (TEA * 32 / NT); ++it) {                             \
      const int i = t + NT * it;                                               \
      const int r = i >> 5;                                                    \
      const int c4 = (i & 31) << 2;                                            \
      float4 v = make_float4(0.f, 0.f, 0.f, 0.f);                              \
      if (r < nrow) v = *(const float4*)((Xptr) + (size_t)(row0 + r) * Dd + c4); \
      ushort4 hv, lv; float rm;                                                \
      hv.x = bfsplit(v.x, &rm); lv.x = bftrunc(rm);                            \
      hv.y = bfsplit(v.y, &rm); lv.y = bftrunc(rm);                            \
      hv.z = bfsplit(v.z, &rm); lv.z = bftrunc(rm);                            \
      hv.w = bfsplit(v.w, &rm); lv.w = bftrunc(rm);                            \
      *(ushort4*)(&Sh[r * LSTR + c4]) = hv;                                    \
      *(ushort4*)(&Sl[r * LSTR + c4]) = lv;                                    \
    }                                                                          \
  }

#define MFMA_PRELUDE(MT)                                         \
  const int lane = t & 63;                                       \
  const int wave = t >> 6;                                       \
  const int l15 = lane & 15;                                     \
  const int q8 = lane >> 4;                                      \
  const int w32 = wave * 32;                                     \
  const int nt0 = wave * 2;                                      \
  f32x4 acc[MT][2];

// Per-direction parameter pack: packed hi bases (lo = +16384) + biases.
struct DirP {
  const ushort *u1, *u2, *p1, *p2;             // upd w1/w2, msg w1/w2 (packed)
  const float *ub1, *ub2, *pb1, *pb2;
};

struct WPtrs { const float* w[10]; };

// ---------------------------------------------------------------------------
// CSR build via 2-level bucket sort (bucket = node >> 8, 196 buckets).
// pairs[dir][i] = (key << 16) | val  (both < 65536 since N = 50000).
// ---------------------------------------------------------------------------
__global__ __launch_bounds__(256) void csr_count(
    const int* __restrict__ src, const int* __restrict__ dst,
    int* __restrict__ bcnt)
{
  const int dirv = blockIdx.y;
  const int* key = dirv ? src : dst;
  __shared__ int h[NBUK];
  const int t = threadIdx.x;
  if (t < NBUK) h[t] = 0;
  __syncthreads();
  const int e0 = blockIdx.x * SCH;
  #pragma unroll
  for (int i = 0; i < SCH / 256; ++i) {
    const int e = e0 + i * 256 + t;
    if (e < Ee) atomicAdd(&h[key[e] >> 8], 1);
  }
  __syncthreads();
  if (t < NBUK && h[t] > 0) atomicAdd(&bcnt[dirv * 256 + t], h[t]);
}

// block 0: bucket scan; blocks 1..640: weight packing (independent work,
// fused to hide the serial scan behind the pack kernel's runtime).
__global__ __launch_bounds__(256) void csr_scan_pack(
    const int* __restrict__ bcnt, int* __restrict__ bbase,
    int* __restrict__ bcur, int* __restrict__ rp,
    WPtrs P, ushort* __restrict__ out)
{
  const int t = threadIdx.x;
  if (blockIdx.x == 0) {
    __shared__ int s[256];
    for (int y = 0; y < 2; ++y) {
      const int v = (t < NBUK) ? bcnt[y * 256 + t] : 0;
      s[t] = v;
      __syncthreads();
      for (int off = 1; off < 256; off <<= 1) {
        int x = s[t];
        if (t >= off) x += s[t - off];
        __syncthreads();
        s[t] = x;
        __syncthreads();
      }
      const int excl = s[t] - v;
      if (t < NBUK) { bbase[y * 257 + t] = excl; bcur[y * 256 + t] = excl; }
      if (t == NBUK - 1) bbase[y * 257 + NBUK] = s[t];
      if (t == 0) rp[y * (Nn + 1) + Nn] = Ee;
      __syncthreads();
    }
  } else {
    const int work = (blockIdx.x - 1) * 256 + t;  // 0..163839
    const int mat = work >> 14;                   // /16384
    const int id = work & 16383;
    const int j = id & 7;
    const int lane = (id >> 3) & 63;
    const int ch = (id >> 9) & 3;
    const int nt = id >> 11;
    const int k = ch * 32 + (lane >> 4) * 8 + j;
    const int n = nt * 16 + (lane & 15);
    const float x = P.w[mat][k * Dd + n];
    float rm;
    const ushort h = bfsplit(x, &rm);
    out[(size_t)mat * WSLOT + id] = h;
    out[(size_t)mat * WSLOT + 16384 + id] = bftrunc(rm);
  }
}

// ---------------------------------------------------------------------------
// Fused kernel: blocks [0, 2*SB) = CSR scatter (compact append at pre-scanned
// bases); blocks [2*SB, ...) = stmsg. Messages stored as fp8 e4m3fn.
// ---------------------------------------------------------------------------
__global__ __launch_bounds__(NT) void scatter_stmsg_kernel(
    const int* __restrict__ src, const int* __restrict__ dst,
    int* __restrict__ bcur, uint* __restrict__ pairs,
    const float* __restrict__ X,
    const ushort* __restrict__ Wn1, const ushort* __restrict__ Wn2,
    const float* __restrict__ Bn1, const float* __restrict__ Bn2,
    DirP pf, DirP pb,
    float* __restrict__ st, u8* __restrict__ Mf, u8* __restrict__ Mb,
    int nScatter)
{
  __shared__ __align__(16) ushort Sbuf[2 * TEA * LSTR];  // 17.4 KB
  const int t = threadIdx.x;

  if ((int)blockIdx.x < nScatter) {
    // ---- scatter branch (R12-verified body) ----
    int* lh = (int*)Sbuf;
    int* gb = lh + 256;
    int* lc = gb + 256;
    const int dirv = (int)blockIdx.x >= SB;
    const int sb = blockIdx.x - dirv * SB;
    const int* key = dirv ? src : dst;
    const int* val = dirv ? dst : src;
    if (t < NBUK) { lh[t] = 0; lc[t] = 0; }
    __syncthreads();
    const int e0 = sb * SCH;
    int ks[SCH / 256], vs[SCH / 256];
    #pragma unroll
    for (int i = 0; i < SCH / 256; ++i) {
      const int e = e0 + i * 256 + t;
      ks[i] = (e < Ee) ? key[e] : -1;
      vs[i] = (e < Ee) ? val[e] : 0;
      if (ks[i] >= 0) atomicAdd(&lh[ks[i] >> 8], 1);
    }
    __syncthreads();
    if (t < NBUK && lh[t] > 0) gb[t] = atomicAdd(&bcur[dirv * 256 + t], lh[t]);
    __syncthreads();
    uint* pd = pairs + (size_t)dirv * Ee;
    #pragma unroll
    for (int i = 0; i < SCH / 256; ++i) {
      if (ks[i] >= 0) {
        const int b = ks[i] >> 8;
        const int r = atomicAdd(&lc[b], 1);
        pd[gb[b] + r] = ((uint)ks[i] << 16) | (uint)vs[i];
      }
    }
    return;
  }

  // ---- stmsg branch ----
  ushort* Sh = Sbuf;
  ushort* Sl = Sbuf + TEA * LSTR;
  const int bid = blockIdx.x - nScatter;
  const int row0 = bid * TEA;
  const int rem = Nn - row0;
  const int nrow = rem < TEA ? rem : TEA;

  STAGE_ROWS(X);
  __syncthreads();
  MFMA_PRELUDE(2);

  // ---- nt MLP -> stc ----
  ZERO_ACC(2);
  MFMA_LAYER(Wn1, Wn1 + 16384, 2);
  __syncthreads();
  HIDDEN_TO_LDS(Bn1, 2);
  __syncthreads();
  ZERO_ACC(2);
  MFMA_LAYER(Wn2, Wn2 + 16384, 2);

  float stc[2][2][4];
  {
    const float b2a = Bn2[w32 + l15];
    const float b2b = Bn2[w32 + 16 + l15];
    #pragma unroll
    for (int mt = 0; mt < 2; ++mt)
      #pragma unroll
      for (int nl = 0; nl < 2; ++nl) {
        const int col = w32 + nl * 16 + l15;
        const float bb = nl ? b2b : b2a;
        #pragma unroll
        for (int rg = 0; rg < 4; ++rg) {
          const int row = mt * 16 + q8 * 4 + rg;
          const float v = acc[mt][nl][rg] + bb;
          stc[mt][nl][rg] = v;
          if (row < nrow) st[(size_t)(row0 + row) * Dd + col] = v;
        }
      }
  }
  __syncthreads();  // hidden tile fully consumed

  // ---- fwd msg MLP on stc ----
  STC_TO_LDS(2);
  __syncthreads();
  ZERO_ACC(2);
  MFMA_LAYER(pf.p1, pf.p1 + 16384, 2);
  __syncthreads();
  HIDDEN_TO_LDS(pf.pb1, 2);
  __syncthreads();
  ZERO_ACC(2);
  MFMA_LAYER(pf.p2, pf.p2 + 16384, 2);
  {
    const float b2a = pf.pb2[w32 + l15];
    const float b2b = pf.pb2[w32 + 16 + l15];
    #pragma unroll
    for (int mt = 0; mt < 2; ++mt)
      #pragma unroll
      for (int nl = 0; nl < 2; ++nl) {
        const int col = w32 + nl * 16 + l15;
        const float bb = nl ? b2b : b2a;
        #pragma unroll
        for (int rg = 0; rg < 4; ++rg) {
          const int row = mt * 16 + q8 * 4 + rg;
          if (row < nrow)
            Mf[(size_t)(row0 + row) * Dd + col] =
                f32_to_e4m3(fmaxf(acc[mt][nl][rg] + bb, 0.f));
        }
      }
  }
  __syncthreads();

  // ---- bwd msg MLP on stc ----
  STC_TO_LDS(2);
  __syncthreads();
  ZERO_ACC(2);
  MFMA_LAYER(pb.p1, pb.p1 + 16384, 2);
  __syncthreads();
  HIDDEN_TO_LDS(pb.pb1, 2);
  __syncthreads();
  ZERO_ACC(2);
  MFMA_LAYER(pb.p2, pb.p2 + 16384, 2);
  {
    const float b2a = pb.pb2[w32 + l15];
    const float b2b = pb.pb2[w32 + 16 + l15];
    #pragma unroll
    for (int mt = 0; mt < 2; ++mt)
      #pragma unroll
      for (int nl = 0; nl < 2; ++nl) {
        const int col = w32 + nl * 16 + l15;
        const float bb = nl ? b2b : b2a;
        #pragma unroll
        for (int rg = 0; rg < 4; ++rg) {
          const int row = mt * 16 + q8 * 4 + rg;
          if (row < nrow)
            Mb[(size_t)(row0 + row) * Dd + col] =
                f32_to_e4m3(fmaxf(acc[mt][nl][rg] + bb, 0.f));
        }
      }
  }
}

// LDS pair staging + 8-band src-ordered emit (band = src>>13).  [R12 exact]
__global__ __launch_bounds__(256) void csr_final(
    const uint* __restrict__ pairs, const int* __restrict__ bbase,
    int* __restrict__ rp, int* __restrict__ col_f, int* __restrict__ col_b)
{
  const int dirv = blockIdx.y;
  const int b = blockIdx.x;
  const int base = bbase[dirv * 257 + b];
  const int cnt = bbase[dirv * 257 + b + 1] - base;
  const uint* pd = pairs + (size_t)dirv * Ee + base;
  int* colo = dirv ? col_b : col_f;
  __shared__ int h[256];
  __shared__ int s[256];
  __shared__ uint pr[FCAP];   // staged pairs (22.5 KB)
  const int t = threadIdx.x;
  h[t] = 0;
  __syncthreads();
  const bool fits = (cnt <= FCAP);
  if (fits) {
    for (int i = t; i < cnt; i += 256) {
      const uint p = pd[i];
      pr[i] = p;
      atomicAdd(&h[(p >> 16) & 255], 1);
    }
  } else {
    for (int i = t; i < cnt; i += 256) atomicAdd(&h[(pd[i] >> 16) & 255], 1);
  }
  __syncthreads();
  const int v = h[t];
  s[t] = v;
  __syncthreads();
  for (int off = 1; off < 256; off <<= 1) {
    int x = s[t];
    if (t >= off) x += s[t - off];
    __syncthreads();
    s[t] = x;
    __syncthreads();
  }
  const int excl = s[t] - v;
  const int node = b * 256 + t;
  if (node < Nn) rp[dirv * (Nn + 1) + node] = base + excl;
  h[t] = excl;  // becomes per-node cursor
  __syncthreads();
  if (fits) {
    for (int band = 0; band < 8; ++band) {
      for (int i = t; i < cnt; i += 256) {
        const uint p = pr[i];
        const int vv = (int)(p & 0xffffu);
        if ((vv >> 13) == band) {
          const int k = (p >> 16) & 255;
          const int r = atomicAdd(&h[k], 1);
          colo[base + r] = vv;
        }
      }
      __syncthreads();
    }
  } else {
    // fallback (statistically unreachable): plain scatter
    for (int i = t; i < cnt; i += 256) {
      const uint p = pd[i];
      const int k = (p >> 16) & 255;
      const int r = atomicAdd(&h[k], 1);
      colo[base + r] = (int)(p & 0xffffu);
    }
  }
}

// ---------------------------------------------------------------------------
// Fused per-round kernel, dual direction (2*1563 blocks, TEA=32 rows).
// Messages are fp8 e4m3fn: row = 128 B = 2 cache lines (half the bf16 line
// count -> gather's miss-token floor halves). Phase A: 8 threads per node
// row; thread o8 owns the 16 fp8 values at bytes o8*16..+15 (one uint4
// load per edge). za/LDS layout identical to the verified bf16 version.
// ---------------------------------------------------------------------------
template <int DO_MSG>
__global__ __launch_bounds__(NT) void aggupdmsg_kernel(
    const u8* __restrict__ Min_f, const u8* __restrict__ Min_b,
    const int* __restrict__ rp_f, const int* __restrict__ rp_b,
    const int* __restrict__ col_f, const int* __restrict__ col_b,
    const float* __restrict__ st,
    u8* __restrict__ RMf, u8* __restrict__ RMb,
    float* __restrict__ RYf, float* __restrict__ RYb, int rstride,
    DirP pf, DirP pb, int nhalf)
{
  __shared__ __align__(16) ushort Sbuf[2 * TEA * LSTR];  // 17.4 KB
  ushort* Sh = Sbuf;
  ushort* Sl = Sbuf + TEA * LSTR;
  const int t = threadIdx.x;
  const int dir = blockIdx.x >= nhalf;
  const int row0 = (blockIdx.x - dir * nhalf) * TEA;
  const int rem = Nn - row0;
  const int nrow = rem < TEA ? rem : TEA;
  const DirP P = dir ? pb : pf;
  const u8* Min = dir ? Min_b : Min_f;
  const int* rp = dir ? rp_b : rp_f;
  const int* col = dir ? col_b : col_f;
  u8* RoutM = dir ? RMb : RMf;
  float* RoutY = dir ? RYb : RYf;
  const int sink = dir ? 0 : (Nn - 1);

  // ---- phase A: gather-sum of fp8 M rows, f32 accumulate ----
  {
    const int nr = t >> 3;           // tile row, 8 threads per row
    const int o8 = t & 7;            // 16B sub-chunk (cols o8*16..+15)
    float4 za[4];
    #pragma unroll
    for (int i = 0; i < 4; ++i) za[i] = make_float4(0.f, 0.f, 0.f, 0.f);
    if (nr < nrow) {
      const int gnode = row0 + nr;
      int e = rp[gnode];
      const int ee = rp[gnode + 1];
      const u8* Mo = Min + o8 * 16;   // o8*16 bytes into each 128B row
      for (; e + 3 < ee; e += 4) {    // 4 independent 16B loads in flight
        const int c0 = col[e];
        const int c1 = col[e + 1];
        const int c2 = col[e + 2];
        const int c3 = col[e + 3];
        uint4 v0 = *(const uint4*)(Mo + (size_t)c0 * Dd);
        uint4 v1 = *(const uint4*)(Mo + (size_t)c1 * Dd);
        uint4 v2 = *(const uint4*)(Mo + (size_t)c2 * Dd);
        uint4 v3 = *(const uint4*)(Mo + (size_t)c3 * Dd);
        DEC16(v0, za); DEC16(v1, za); DEC16(v2, za); DEC16(v3, za);
      }
      for (; e < ee; ++e) {
        uint4 v = *(const uint4*)(Mo + (size_t)col[e] * Dd);
        DEC16(v, za);
      }
    }
    #pragma unroll
    for (int k = 0; k < 4; ++k) {
      ushort4 hv, lv; float rm;
      hv.x = bfsplit(za[k].x, &rm); lv.x = bftrunc(rm);
      hv.y = bfsplit(za[k].y, &rm); lv.y = bftrunc(rm);
      hv.z = bfsplit(za[k].z, &rm); lv.z = bftrunc(rm);
      hv.w = bfsplit(za[k].w, &rm); lv.w = bftrunc(rm);
      const int c4 = o8 * 16 + k * 4;
      *(ushort4*)(&Sh[nr * LSTR + c4]) = hv;
      *(ushort4*)(&Sl[nr * LSTR + c4]) = lv;
    }
  }
  __syncthreads();

  MFMA_PRELUDE(2);

  // ---- phase B: update MLP ----
  ZERO_ACC(2);
  MFMA_LAYER(P.u1, P.u1 + 16384, 2);
  __syncthreads();
  HIDDEN_TO_LDS(P.ub1, 2);
  __syncthreads();
  ZERO_ACC(2);
  MFMA_LAYER(P.u2, P.u2 + 16384, 2);

  // y = st + relu(acc + ub2), y[sink-row contribution] zeroed
  {
    const float b2a = P.ub2[w32 + l15];
    const float b2b = P.ub2[w32 + 16 + l15];
    if (DO_MSG) __syncthreads();  // all hidden reads done before overwrite
    #pragma unroll
    for (int mt = 0; mt < 2; ++mt)
      #pragma unroll
      for (int nl = 0; nl < 2; ++nl) {
        const int col = w32 + nl * 16 + l15;
        const float bb = nl ? b2b : b2a;
        #pragma unroll
        for (int rg = 0; rg < 4; ++rg) {
          const int row = mt * 16 + q8 * 4 + rg;
          float v = 0.f;
          if (row < nrow) {
            const int gr = row0 + row;
            v = fmaxf(acc[mt][nl][rg] + bb, 0.f);
            if (gr == sink) v = 0.f;
            v += st[(size_t)gr * Dd + col];
          }
          if (DO_MSG) {
            float rm;
            const ushort hh = bfsplit(v, &rm);
            const int off = row * LSTR + col;
            Sh[off] = hh;
            Sl[off] = bftrunc(rm);
          } else if (row < nrow) {
            RoutY[(size_t)(row0 + row) * rstride + col] = v;
          }
        }
      }
  }

  if (DO_MSG) {
    __syncthreads();
    // ---- phase C: msg MLP on y-tile ----
    ZERO_ACC(2);
    MFMA_LAYER(P.p1, P.p1 + 16384, 2);
    __syncthreads();
    HIDDEN_TO_LDS(P.pb1, 2);
    __syncthreads();
    ZERO_ACC(2);
    MFMA_LAYER(P.p2, P.p2 + 16384, 2);

    const float b2a = P.pb2[w32 + l15];
    const float b2b = P.pb2[w32 + 16 + l15];
    #pragma unroll
    for (int mt = 0; mt < 2; ++mt)
      #pragma unroll
      for (int nl = 0; nl < 2; ++nl) {
        const int col = w32 + nl * 16 + l15;
        const float bb = nl ? b2b : b2a;
        #pragma unroll
        for (int rg = 0; rg < 4; ++rg) {
          const int row = mt * 16 + q8 * 4 + rg;
          if (row < nrow)
            RoutM[(size_t)(row0 + row) * Dd + col] =
                f32_to_e4m3(fmaxf(acc[mt][nl][rg] + bb, 0.f));
        }
      }
  }
}

// ---------------------------------------------------------------------------
extern "C" void kernel_launch(void* const* d_in, const int* in_sizes, int n_in,
                              void* d_out, int out_size, void* d_ws, size_t ws_size,
                              hipStream_t stream)
{
  const float* feat = (const float*)d_in[0];
  const int*   src  = (const int*)d_in[1];
  const int*   dst  = (const int*)d_in[2];

  const float* W[5][4];
  for (int p = 0; p < 5; ++p)
    for (int q = 0; q < 4; ++q)
      W[p][q] = (const float*)d_in[3 + p * 4 + q];

  // workspace: st(f32) + 4x fp8 M arrays + CSR + packed weights
  float* st = (float*)d_ws;                          // [N,D] f32
  u8* Mp_f = (u8*)(st + (size_t)Nn * Dd);            // ping fwd [N,D] fp8
  u8* Mp_b = Mp_f + (size_t)Nn * Dd;                 // ping bwd
  u8* Mq_f = Mp_b + (size_t)Nn * Dd;                 // pong fwd
  u8* Mq_b = Mq_f + (size_t)Nn * Dd;                 // pong bwd
  int* ip       = (int*)(Mq_b + (size_t)Nn * Dd);
  int* rp_f     = ip;                 ip += Nn + 1;  // rp_b contiguous after
  int* rp_b     = ip;                 ip += Nn + 1;
  int* col_f    = ip;                 ip += Ee;
  int* col_b    = ip;                 ip += Ee;
  int* bcnt     = ip;                 ip += 2 * 256;
  int* bbase    = ip;                 ip += 2 * 257;
  int* bcur     = ip;                 ip += 2 * 256;
  ushort* Wp = (ushort*)(((uintptr_t)ip + 63) & ~(uintptr_t)63);  // 640 KB
  float* out = (float*)d_out;                        // [N, 2D] f32

  // pairs buffer (6.4 MB) aliases the Mq pong region (12.8 MB): CSR build
  // completes (stream-ordered) before round 1 writes Mq.
  uint* pairs = (uint*)Mq_f;

  const int aggBlocks  = (Nn + TEA - 1) / TEA;    // 1563 tiles
  const int dualBlocks = 2 * aggBlocks;           // 3126
  const int nScatter   = 2 * SB;                  // 782

  WPtrs wpk;  // slots: 2p = W[p].w1, 2p+1 = W[p].w2
  for (int p = 0; p < 5; ++p) { wpk.w[2 * p] = W[p][0]; wpk.w[2 * p + 1] = W[p][2]; }

  #define WS(m) (Wp + (size_t)(m) * WSLOT)
  // fwd: upd = fu (p=2), msg = fp (p=1); bwd: upd = bu (p=4), msg = bp (p=3)
  DirP Pf = { WS(4), WS(5), WS(2), WS(3), W[2][1], W[2][3], W[1][1], W[1][3] };
  DirP Pb = { WS(8), WS(9), WS(6), WS(7), W[4][1], W[4][3], W[3][1], W[3][3] };

  // ---- CSR build + fused scatter/stmsg ----
  hipMemsetAsync(bcnt, 0, 2 * 256 * sizeof(int), stream);
  csr_count<<<dim3(SB, 2), 256, 0, stream>>>(src, dst, bcnt);
  csr_scan_pack<<<641, 256, 0, stream>>>(bcnt, bbase, bcur, rp_f, wpk, Wp);
  scatter_stmsg_kernel<<<nScatter + aggBlocks, NT, 0, stream>>>(
      src, dst, bcur, pairs, feat, WS(0), WS(1), W[0][1], W[0][3],
      Pf, Pb, st, Mp_f, Mp_b, nScatter);
  csr_final<<<dim3(NBUK, 2), 256, 0, stream>>>(pairs, bbase, rp_f, col_f, col_b);

  // ---- round 1: agg+upd+msg, ping -> pong ----
  aggupdmsg_kernel<1><<<dualBlocks, NT, 0, stream>>>(
      Mp_f, Mp_b, rp_f, rp_b, col_f, col_b, st,
      Mq_f, Mq_b, nullptr, nullptr, 0, Pf, Pb, aggBlocks);

  // ---- round 2: agg+upd+msg, pong -> ping ----
  aggupdmsg_kernel<1><<<dualBlocks, NT, 0, stream>>>(
      Mq_f, Mq_b, rp_f, rp_b, col_f, col_b, st,
      Mp_f, Mp_b, nullptr, nullptr, 0, Pf, Pb, aggBlocks);

  // ---- round 3 (final): agg+upd, ping -> y into out column-halves ----
  aggupdmsg_kernel<0><<<dualBlocks, NT, 0, stream>>>(
      Mp_f, Mp_b, rp_f, rp_b, col_f, col_b, st,
      nullptr, nullptr, out, out + Dd, 2 * Dd, Pf, Pb, aggBlocks);

  #undef WS
}

// Round 14
// 488.095 us; speedup vs baseline: 1.1609x; 1.1609x over previous
//
#include <hip/hip_runtime.h>

// Problem constants (reference: N=50000 nodes, E=800000 edges, D=128, K=3)
#define Nn 50000
#define Ee 800000
#define Dd 128
#define Kk 3
#define TEA 32   // rows per block tile (17.4 KB LDS)
#define NT 256   // threads per block (4 waves)

// LDS bf16 tile row stride (ushorts): 128 + 8 pad
#define LSTR 136
// Per-matrix packed-weight slot: hi[16384] + lo[16384] ushorts
#define WSLOT 32768

// Bucket sort CSR build: bucket = node >> 8 (196 buckets for N=50000)
#define NBUK 196
#define SCH 2048                      // edges per sort block
#define SB ((Ee + SCH - 1) / SCH)     // 391 blocks per direction
#define FCAP 5632                     // csr_final LDS staging capacity

typedef short sh8 __attribute__((ext_vector_type(8)));    // 8 bf16 (4 VGPRs)
typedef float f32x4 __attribute__((ext_vector_type(4)));  // MFMA C/D
typedef unsigned char u8;

// Split fp32 into bf16 hi (truncate) + bf16 lo (residual, truncate).
__device__ __forceinline__ ushort bfsplit(float x, float* rem) {
  const unsigned u = __float_as_uint(x);
  *rem = x - __uint_as_float(u & 0xffff0000u);
  return (ushort)(u >> 16);
}
__device__ __forceinline__ ushort bftrunc(float x) {
  return (ushort)(__float_as_uint(x) >> 16);
}

// ---- fp8 OCP e4m3fn (software, self-consistent pair; x >= 0 after relu) ----
// encode: RNE at 3-bit mantissa; denormals via round(x*512); clip to 448.
__device__ __forceinline__ u8 f32_to_e4m3(float x) {
  x = fminf(x, 448.f);
  if (x < 0.015625f) return (u8)__float2int_rn(x * 512.f);   // denorm/zero
  const unsigned u = __float_as_uint(x);
  const unsigned r = u + 0x7FFFFu + ((u >> 20) & 1u);        // RNE carry-safe
  const unsigned e = (r >> 23) - 120u;                       // 1..15
  return (u8)((e << 3) | ((r >> 20) & 7u));
}
// decode (branch-free, bit-exact for ALL codes incl. denorm/zero):
// as_float(b<<20) * 2^120.  Normals: +120 on exponent == the bias trick.
// Denorm b<8: f32-denorm b*2^-129 scaled by 2^120 = b*2^-9 exactly.
#define E4M3_SCALE 1.329227995784916e+36f  /* 0x1p120 */
// accumulate 4 fp8 bytes packed in a uint into a float4 (3 VALU ops/byte)
__device__ __forceinline__ void accq(unsigned u, float4& a) {
  a.x = fmaf(__uint_as_float((u & 0x000000FFu) << 20), E4M3_SCALE, a.x);
  a.y = fmaf(__uint_as_float((u & 0x0000FF00u) << 12), E4M3_SCALE, a.y);
  a.z = fmaf(__uint_as_float((u & 0x00FF0000u) << 4),  E4M3_SCALE, a.z);
  a.w = fmaf(__uint_as_float((u >> 4) & 0x0FF00000u),  E4M3_SCALE, a.w);
}
#define DEC16(v, za) { accq((v).x, za[0]); accq((v).y, za[1]); \
                       accq((v).z, za[2]); accq((v).w, za[3]); }

// (MT*16)x128x128 layer on MFMA 16x16x32_bf16, split-bf16 (3 products).
#define MFMA_LAYER(WH, WL, MT)                                                 \
  {                                                                            \
    _Pragma("unroll")                                                          \
    for (int c = 0; c < 4; ++c) {                                              \
      const sh8 bh0 = *(const sh8*)((WH) + (((nt0    ) * 4 + c) * 64 + lane) * 8); \
      const sh8 bh1 = *(const sh8*)((WH) + (((nt0 + 1) * 4 + c) * 64 + lane) * 8); \
      const sh8 bl0 = *(const sh8*)((WL) + (((nt0    ) * 4 + c) * 64 + lane) * 8); \
      const sh8 bl1 = *(const sh8*)((WL) + (((nt0 + 1) * 4 + c) * 64 + lane) * 8); \
      _Pragma("unroll")                                                        \
      for (int mt = 0; mt < (MT); ++mt) {                                      \
        const int aoff = (mt * 16 + l15) * LSTR + c * 32 + q8 * 8;             \
        const sh8 ah = *(const sh8*)(Sh + aoff);                               \
        const sh8 al = *(const sh8*)(Sl + aoff);                               \
        acc[mt][0] = __builtin_amdgcn_mfma_f32_16x16x32_bf16(ah, bh0, acc[mt][0], 0, 0, 0); \
        acc[mt][1] = __builtin_amdgcn_mfma_f32_16x16x32_bf16(ah, bh1, acc[mt][1], 0, 0, 0); \
        acc[mt][0] = __builtin_amdgcn_mfma_f32_16x16x32_bf16(al, bh0, acc[mt][0], 0, 0, 0); \
        acc[mt][1] = __builtin_amdgcn_mfma_f32_16x16x32_bf16(al, bh1, acc[mt][1], 0, 0, 0); \
        acc[mt][0] = __builtin_amdgcn_mfma_f32_16x16x32_bf16(ah, bl0, acc[mt][0], 0, 0, 0); \
        acc[mt][1] = __builtin_amdgcn_mfma_f32_16x16x32_bf16(ah, bl1, acc[mt][1], 0, 0, 0); \
      }                                                                        \
    }                                                                          \
  }

#define ZERO_ACC(MT)                                             \
  {                                                              \
    _Pragma("unroll")                                            \
    for (int mt = 0; mt < (MT); ++mt)                            \
      _Pragma("unroll")                                          \
      for (int nl = 0; nl < 2; ++nl) {                           \
        acc[mt][nl][0] = 0.f; acc[mt][nl][1] = 0.f;              \
        acc[mt][nl][2] = 0.f; acc[mt][nl][3] = 0.f;              \
      }                                                          \
  }

// hidden = relu(acc + b1) -> split hi/lo back into LDS (C layout -> A layout)
#define HIDDEN_TO_LDS(B1ptr, MT)                                 \
  {                                                              \
    const float b1a = (B1ptr)[w32 + l15];                        \
    const float b1b = (B1ptr)[w32 + 16 + l15];                   \
    _Pragma("unroll")                                            \
    for (int mt = 0; mt < (MT); ++mt)                            \
      _Pragma("unroll")                                          \
      for (int nl = 0; nl < 2; ++nl) {                           \
        const int col = w32 + nl * 16 + l15;                     \
        const float bb = nl ? b1b : b1a;                         \
        _Pragma("unroll")                                        \
        for (int rg = 0; rg < 4; ++rg) {                         \
          const int row = mt * 16 + q8 * 4 + rg;                 \
          const float h = fmaxf(acc[mt][nl][rg] + bb, 0.f);      \
          float rm;                                              \
          const ushort hh = bfsplit(h, &rm);                     \
          const int off = row * LSTR + col;                      \
          Sh[off] = hh;                                          \
          Sl[off] = bftrunc(rm);                                 \
        }                                                        \
      }                                                          \
  }

// stc (C-layout f32, bias included, signed) -> split into LDS A-layout
#define STC_TO_LDS(MT)                                           \
  {                                                              \
    _Pragma("unroll")                                            \
    for (int mt = 0; mt < (MT); ++mt)                            \
      _Pragma("unroll")                                          \
      for (int nl = 0; nl < 2; ++nl) {                           \
        const int col = w32 + nl * 16 + l15;                     \
        _Pragma("unroll")                                        \
        for (int rg = 0; rg < 4; ++rg) {                         \
          const int row = mt * 16 + q8 * 4 + rg;                 \
          float rm;                                              \
          const ushort hh = bfsplit(stc[mt][nl][rg], &rm);       \
          const int off = row * LSTR + col;                      \
          Sh[off] = hh;                                          \
          Sl[off] = bftrunc(rm);                                 \
        }                                                        \
      }                                                          \
  }

// stage rows [row0, row0+nrow) of row-major f32 X (stride Dd) into Sh/Sl split
#define STAGE_ROWS(Xptr)                                                       \
  {                                                                            \
    _Pragma("unroll")                                                          \
    for (int it = 0; it < (TEA * 32 / NT); ++it) {                             \
      const int i = t + NT * it;                                               \
      const int r = i >> 5;                                                    \
      const int c4 = (i & 31) << 2;                                            \
      float4 v = make_float4(0.f, 0.f, 0.f, 0.f);                              \
      if (r < nrow) v = *(const float4*)((Xptr) + (size_t)(row0 + r) * Dd + c4); \
      ushort4 hv, lv; float rm;                                                \
      hv.x = bfsplit(v.x, &rm); lv.x = bftrunc(rm);                            \
      hv.y = bfsplit(v.y, &rm); lv.y = bftrunc(rm);                            \
      hv.z = bfsplit(v.z, &rm); lv.z = bftrunc(rm);                            \
      hv.w = bfsplit(v.w, &rm); lv.w = bftrunc(rm);                            \
      *(ushort4*)(&Sh[r * LSTR + c4]) = hv;                                    \
      *(ushort4*)(&Sl[r * LSTR + c4]) = lv;                                    \
    }                                                                          \
  }

#define MFMA_PRELUDE(MT)                                         \
  const int lane = t & 63;                                       \
  const int wave = t >> 6;                                       \
  const int l15 = lane & 15;                                     \
  const int q8 = lane >> 4;                                      \
  const int w32 = wave * 32;                                     \
  const int nt0 = wave * 2;                                      \
  f32x4 acc[MT][2];

// Per-direction parameter pack: packed hi bases (lo = +16384) + biases.
struct DirP {
  const ushort *u1, *u2, *p1, *p2;             // upd w1/w2, msg w1/w2 (packed)
  const float *ub1, *ub2, *pb1, *pb2;
};

struct WPtrs { const float* w[10]; };

// ---------------------------------------------------------------------------
// CSR build via 2-level bucket sort (bucket = node >> 8, 196 buckets).
// pairs[dir][i] = (key << 16) | val  (both < 65536 since N = 50000).
// ---------------------------------------------------------------------------
__global__ __launch_bounds__(256) void csr_count(
    const int* __restrict__ src, const int* __restrict__ dst,
    int* __restrict__ bcnt)
{
  const int dirv = blockIdx.y;
  const int* key = dirv ? src : dst;
  __shared__ int h[NBUK];
  const int t = threadIdx.x;
  if (t < NBUK) h[t] = 0;
  __syncthreads();
  const int e0 = blockIdx.x * SCH;
  #pragma unroll
  for (int i = 0; i < SCH / 256; ++i) {
    const int e = e0 + i * 256 + t;
    if (e < Ee) atomicAdd(&h[key[e] >> 8], 1);
  }
  __syncthreads();
  if (t < NBUK && h[t] > 0) atomicAdd(&bcnt[dirv * 256 + t], h[t]);
}

// block 0: bucket scan; blocks 1..640: weight packing (independent work,
// fused to hide the serial scan behind the pack kernel's runtime).
__global__ __launch_bounds__(256) void csr_scan_pack(
    const int* __restrict__ bcnt, int* __restrict__ bbase,
    int* __restrict__ bcur, int* __restrict__ rp,
    WPtrs P, ushort* __restrict__ out)
{
  const int t = threadIdx.x;
  if (blockIdx.x == 0) {
    __shared__ int s[256];
    for (int y = 0; y < 2; ++y) {
      const int v = (t < NBUK) ? bcnt[y * 256 + t] : 0;
      s[t] = v;
      __syncthreads();
      for (int off = 1; off < 256; off <<= 1) {
        int x = s[t];
        if (t >= off) x += s[t - off];
        __syncthreads();
        s[t] = x;
        __syncthreads();
      }
      const int excl = s[t] - v;
      if (t < NBUK) { bbase[y * 257 + t] = excl; bcur[y * 256 + t] = excl; }
      if (t == NBUK - 1) bbase[y * 257 + NBUK] = s[t];
      if (t == 0) rp[y * (Nn + 1) + Nn] = Ee;
      __syncthreads();
    }
  } else {
    const int work = (blockIdx.x - 1) * 256 + t;  // 0..163839
    const int mat = work >> 14;                   // /16384
    const int id = work & 16383;
    const int j = id & 7;
    const int lane = (id >> 3) & 63;
    const int ch = (id >> 9) & 3;
    const int nt = id >> 11;
    const int k = ch * 32 + (lane >> 4) * 8 + j;
    const int n = nt * 16 + (lane & 15);
    const float x = P.w[mat][k * Dd + n];
    float rm;
    const ushort h = bfsplit(x, &rm);
    out[(size_t)mat * WSLOT + id] = h;
    out[(size_t)mat * WSLOT + 16384 + id] = bftrunc(rm);
  }
}

// ---------------------------------------------------------------------------
// Fused kernel: blocks [0, 2*SB) = CSR scatter (compact append at pre-scanned
// bases); blocks [2*SB, ...) = stmsg. Messages stored as fp8 e4m3fn.
// ---------------------------------------------------------------------------
__global__ __launch_bounds__(NT) void scatter_stmsg_kernel(
    const int* __restrict__ src, const int* __restrict__ dst,
    int* __restrict__ bcur, uint* __restrict__ pairs,
    const float* __restrict__ X,
    const ushort* __restrict__ Wn1, const ushort* __restrict__ Wn2,
    const float* __restrict__ Bn1, const float* __restrict__ Bn2,
    DirP pf, DirP pb,
    float* __restrict__ st, u8* __restrict__ Mf, u8* __restrict__ Mb,
    int nScatter)
{
  __shared__ __align__(16) ushort Sbuf[2 * TEA * LSTR];  // 17.4 KB
  const int t = threadIdx.x;

  if ((int)blockIdx.x < nScatter) {
    // ---- scatter branch (R12-verified body) ----
    int* lh = (int*)Sbuf;
    int* gb = lh + 256;
    int* lc = gb + 256;
    const int dirv = (int)blockIdx.x >= SB;
    const int sb = blockIdx.x - dirv * SB;
    const int* key = dirv ? src : dst;
    const int* val = dirv ? dst : src;
    if (t < NBUK) { lh[t] = 0; lc[t] = 0; }
    __syncthreads();
    const int e0 = sb * SCH;
    int ks[SCH / 256], vs[SCH / 256];
    #pragma unroll
    for (int i = 0; i < SCH / 256; ++i) {
      const int e = e0 + i * 256 + t;
      ks[i] = (e < Ee) ? key[e] : -1;
      vs[i] = (e < Ee) ? val[e] : 0;
      if (ks[i] >= 0) atomicAdd(&lh[ks[i] >> 8], 1);
    }
    __syncthreads();
    if (t < NBUK && lh[t] > 0) gb[t] = atomicAdd(&bcur[dirv * 256 + t], lh[t]);
    __syncthreads();
    uint* pd = pairs + (size_t)dirv * Ee;
    #pragma unroll
    for (int i = 0; i < SCH / 256; ++i) {
      if (ks[i] >= 0) {
        const int b = ks[i] >> 8;
        const int r = atomicAdd(&lc[b], 1);
        pd[gb[b] + r] = ((uint)ks[i] << 16) | (uint)vs[i];
      }
    }
    return;
  }

  // ---- stmsg branch ----
  ushort* Sh = Sbuf;
  ushort* Sl = Sbuf + TEA * LSTR;
  const int bid = blockIdx.x - nScatter;
  const int row0 = bid * TEA;
  const int rem = Nn - row0;
  const int nrow = rem < TEA ? rem : TEA;

  STAGE_ROWS(X);
  __syncthreads();
  MFMA_PRELUDE(2);

  // ---- nt MLP -> stc ----
  ZERO_ACC(2);
  MFMA_LAYER(Wn1, Wn1 + 16384, 2);
  __syncthreads();
  HIDDEN_TO_LDS(Bn1, 2);
  __syncthreads();
  ZERO_ACC(2);
  MFMA_LAYER(Wn2, Wn2 + 16384, 2);

  float stc[2][2][4];
  {
    const float b2a = Bn2[w32 + l15];
    const float b2b = Bn2[w32 + 16 + l15];
    #pragma unroll
    for (int mt = 0; mt < 2; ++mt)
      #pragma unroll
      for (int nl = 0; nl < 2; ++nl) {
        const int col = w32 + nl * 16 + l15;
        const float bb = nl ? b2b : b2a;
        #pragma unroll
        for (int rg = 0; rg < 4; ++rg) {
          const int row = mt * 16 + q8 * 4 + rg;
          const float v = acc[mt][nl][rg] + bb;
          stc[mt][nl][rg] = v;
          if (row < nrow) st[(size_t)(row0 + row) * Dd + col] = v;
        }
      }
  }
  __syncthreads();  // hidden tile fully consumed

  // ---- fwd msg MLP on stc ----
  STC_TO_LDS(2);
  __syncthreads();
  ZERO_ACC(2);
  MFMA_LAYER(pf.p1, pf.p1 + 16384, 2);
  __syncthreads();
  HIDDEN_TO_LDS(pf.pb1, 2);
  __syncthreads();
  ZERO_ACC(2);
  MFMA_LAYER(pf.p2, pf.p2 + 16384, 2);
  {
    const float b2a = pf.pb2[w32 + l15];
    const float b2b = pf.pb2[w32 + 16 + l15];
    #pragma unroll
    for (int mt = 0; mt < 2; ++mt)
      #pragma unroll
      for (int nl = 0; nl < 2; ++nl) {
        const int col = w32 + nl * 16 + l15;
        const float bb = nl ? b2b : b2a;
        #pragma unroll
        for (int rg = 0; rg < 4; ++rg) {
          const int row = mt * 16 + q8 * 4 + rg;
          if (row < nrow)
            Mf[(size_t)(row0 + row) * Dd + col] =
                f32_to_e4m3(fmaxf(acc[mt][nl][rg] + bb, 0.f));
        }
      }
  }
  __syncthreads();

  // ---- bwd msg MLP on stc ----
  STC_TO_LDS(2);
  __syncthreads();
  ZERO_ACC(2);
  MFMA_LAYER(pb.p1, pb.p1 + 16384, 2);
  __syncthreads();
  HIDDEN_TO_LDS(pb.pb1, 2);
  __syncthreads();
  ZERO_ACC(2);
  MFMA_LAYER(pb.p2, pb.p2 + 16384, 2);
  {
    const float b2a = pb.pb2[w32 + l15];
    const float b2b = pb.pb2[w32 + 16 + l15];
    #pragma unroll
    for (int mt = 0; mt < 2; ++mt)
      #pragma unroll
      for (int nl = 0; nl < 2; ++nl) {
        const int col = w32 + nl * 16 + l15;
        const float bb = nl ? b2b : b2a;
        #pragma unroll
        for (int rg = 0; rg < 4; ++rg) {
          const int row = mt * 16 + q8 * 4 + rg;
          if (row < nrow)
            Mb[(size_t)(row0 + row) * Dd + col] =
                f32_to_e4m3(fmaxf(acc[mt][nl][rg] + bb, 0.f));
        }
      }
  }
}

// LDS pair staging + 8-band src-ordered emit (band = src>>13).  [R12 exact]
__global__ __launch_bounds__(256) void csr_final(
    const uint* __restrict__ pairs, const int* __restrict__ bbase,
    int* __restrict__ rp, int* __restrict__ col_f, int* __restrict__ col_b)
{
  const int dirv = blockIdx.y;
  const int b = blockIdx.x;
  const int base = bbase[dirv * 257 + b];
  const int cnt = bbase[dirv * 257 + b + 1] - base;
  const uint* pd = pairs + (size_t)dirv * Ee + base;
  int* colo = dirv ? col_b : col_f;
  __shared__ int h[256];
  __shared__ int s[256];
  __shared__ uint pr[FCAP];   // staged pairs (22.5 KB)
  const int t = threadIdx.x;
  h[t] = 0;
  __syncthreads();
  const bool fits = (cnt <= FCAP);
  if (fits) {
    for (int i = t; i < cnt; i += 256) {
      const uint p = pd[i];
      pr[i] = p;
      atomicAdd(&h[(p >> 16) & 255], 1);
    }
  } else {
    for (int i = t; i < cnt; i += 256) atomicAdd(&h[(pd[i] >> 16) & 255], 1);
  }
  __syncthreads();
  const int v = h[t];
  s[t] = v;
  __syncthreads();
  for (int off = 1; off < 256; off <<= 1) {
    int x = s[t];
    if (t >= off) x += s[t - off];
    __syncthreads();
    s[t] = x;
    __syncthreads();
  }
  const int excl = s[t] - v;
  const int node = b * 256 + t;
  if (node < Nn) rp[dirv * (Nn + 1) + node] = base + excl;
  h[t] = excl;  // becomes per-node cursor
  __syncthreads();
  if (fits) {
    for (int band = 0; band < 8; ++band) {
      for (int i = t; i < cnt; i += 256) {
        const uint p = pr[i];
        const int vv = (int)(p & 0xffffu);
        if ((vv >> 13) == band) {
          const int k = (p >> 16) & 255;
          const int r = atomicAdd(&h[k], 1);
          colo[base + r] = vv;
        }
      }
      __syncthreads();
    }
  } else {
    // fallback (statistically unreachable): plain scatter
    for (int i = t; i < cnt; i += 256) {
      const uint p = pd[i];
      const int k = (p >> 16) & 255;
      const int r = atomicAdd(&h[k], 1);
      colo[base + r] = (int)(p & 0xffffu);
    }
  }
}

// ---------------------------------------------------------------------------
// Fused per-round kernel, dual direction (2*1563 blocks, TEA=32 rows).
// Messages fp8 e4m3fn: row = 128 B = 2 cache lines. Phase A: 8 threads per
// node row; thread o8 owns bytes o8*16..+15 (one uint4 load per edge);
// branch-free 3-op/byte decode via as_float(b<<20)*2^120 (bit-exact).
// ---------------------------------------------------------------------------
template <int DO_MSG>
__global__ __launch_bounds__(NT) void aggupdmsg_kernel(
    const u8* __restrict__ Min_f, const u8* __restrict__ Min_b,
    const int* __restrict__ rp_f, const int* __restrict__ rp_b,
    const int* __restrict__ col_f, const int* __restrict__ col_b,
    const float* __restrict__ st,
    u8* __restrict__ RMf, u8* __restrict__ RMb,
    float* __restrict__ RYf, float* __restrict__ RYb, int rstride,
    DirP pf, DirP pb, int nhalf)
{
  __shared__ __align__(16) ushort Sbuf[2 * TEA * LSTR];  // 17.4 KB
  ushort* Sh = Sbuf;
  ushort* Sl = Sbuf + TEA * LSTR;
  const int t = threadIdx.x;
  const int dir = blockIdx.x >= nhalf;
  const int row0 = (blockIdx.x - dir * nhalf) * TEA;
  const int rem = Nn - row0;
  const int nrow = rem < TEA ? rem : TEA;
  const DirP P = dir ? pb : pf;
  const u8* Min = dir ? Min_b : Min_f;
  const int* rp = dir ? rp_b : rp_f;
  const int* col = dir ? col_b : col_f;
  u8* RoutM = dir ? RMb : RMf;
  float* RoutY = dir ? RYb : RYf;
  const int sink = dir ? 0 : (Nn - 1);

  // ---- phase A: gather-sum of fp8 M rows, f32 accumulate ----
  {
    const int nr = t >> 3;           // tile row, 8 threads per row
    const int o8 = t & 7;            // 16B sub-chunk (cols o8*16..+15)
    float4 za[4];
    #pragma unroll
    for (int i = 0; i < 4; ++i) za[i] = make_float4(0.f, 0.f, 0.f, 0.f);
    if (nr < nrow) {
      const int gnode = row0 + nr;
      int e = rp[gnode];
      const int ee = rp[gnode + 1];
      const u8* Mo = Min + o8 * 16;   // o8*16 bytes into each 128B row
      for (; e + 3 < ee; e += 4) {    // 4 independent 16B loads in flight
        const int c0 = col[e];
        const int c1 = col[e + 1];
        const int c2 = col[e + 2];
        const int c3 = col[e + 3];
        uint4 v0 = *(const uint4*)(Mo + (size_t)c0 * Dd);
        uint4 v1 = *(const uint4*)(Mo + (size_t)c1 * Dd);
        uint4 v2 = *(const uint4*)(Mo + (size_t)c2 * Dd);
        uint4 v3 = *(const uint4*)(Mo + (size_t)c3 * Dd);
        DEC16(v0, za); DEC16(v1, za); DEC16(v2, za); DEC16(v3, za);
      }
      for (; e < ee; ++e) {
        uint4 v = *(const uint4*)(Mo + (size_t)col[e] * Dd);
        DEC16(v, za);
      }
    }
    #pragma unroll
    for (int k = 0; k < 4; ++k) {
      ushort4 hv, lv; float rm;
      hv.x = bfsplit(za[k].x, &rm); lv.x = bftrunc(rm);
      hv.y = bfsplit(za[k].y, &rm); lv.y = bftrunc(rm);
      hv.z = bfsplit(za[k].z, &rm); lv.z = bftrunc(rm);
      hv.w = bfsplit(za[k].w, &rm); lv.w = bftrunc(rm);
      const int c4 = o8 * 16 + k * 4;
      *(ushort4*)(&Sh[nr * LSTR + c4]) = hv;
      *(ushort4*)(&Sl[nr * LSTR + c4]) = lv;
    }
  }
  __syncthreads();

  MFMA_PRELUDE(2);

  // ---- phase B: update MLP ----
  ZERO_ACC(2);
  MFMA_LAYER(P.u1, P.u1 + 16384, 2);
  __syncthreads();
  HIDDEN_TO_LDS(P.ub1, 2);
  __syncthreads();
  ZERO_ACC(2);
  MFMA_LAYER(P.u2, P.u2 + 16384, 2);

  // y = st + relu(acc + ub2), y[sink-row contribution] zeroed
  {
    const float b2a = P.ub2[w32 + l15];
    const float b2b = P.ub2[w32 + 16 + l15];
    if (DO_MSG) __syncthreads();  // all hidden reads done before overwrite
    #pragma unroll
    for (int mt = 0; mt < 2; ++mt)
      #pragma unroll
      for (int nl = 0; nl < 2; ++nl) {
        const int col = w32 + nl * 16 + l15;
        const float bb = nl ? b2b : b2a;
        #pragma unroll
        for (int rg = 0; rg < 4; ++rg) {
          const int row = mt * 16 + q8 * 4 + rg;
          float v = 0.f;
          if (row < nrow) {
            const int gr = row0 + row;
            v = fmaxf(acc[mt][nl][rg] + bb, 0.f);
            if (gr == sink) v = 0.f;
            v += st[(size_t)gr * Dd + col];
          }
          if (DO_MSG) {
            float rm;
            const ushort hh = bfsplit(v, &rm);
            const int off = row * LSTR + col;
            Sh[off] = hh;
            Sl[off] = bftrunc(rm);
          } else if (row < nrow) {
            RoutY[(size_t)(row0 + row) * rstride + col] = v;
          }
        }
      }
  }

  if (DO_MSG) {
    __syncthreads();
    // ---- phase C: msg MLP on y-tile ----
    ZERO_ACC(2);
    MFMA_LAYER(P.p1, P.p1 + 16384, 2);
    __syncthreads();
    HIDDEN_TO_LDS(P.pb1, 2);
    __syncthreads();
    ZERO_ACC(2);
    MFMA_LAYER(P.p2, P.p2 + 16384, 2);

    const float b2a = P.pb2[w32 + l15];
    const float b2b = P.pb2[w32 + 16 + l15];
    #pragma unroll
    for (int mt = 0; mt < 2; ++mt)
      #pragma unroll
      for (int nl = 0; nl < 2; ++nl) {
        const int col = w32 + nl * 16 + l15;
        const float bb = nl ? b2b : b2a;
        #pragma unroll
        for (int rg = 0; rg < 4; ++rg) {
          const int row = mt * 16 + q8 * 4 + rg;
          if (row < nrow)
            RoutM[(size_t)(row0 + row) * Dd + col] =
                f32_to_e4m3(fmaxf(acc[mt][nl][rg] + bb, 0.f));
        }
      }
  }
}

// ---------------------------------------------------------------------------
extern "C" void kernel_launch(void* const* d_in, const int* in_sizes, int n_in,
                              void* d_out, int out_size, void* d_ws, size_t ws_size,
                              hipStream_t stream)
{
  const float* feat = (const float*)d_in[0];
  const int*   src  = (const int*)d_in[1];
  const int*   dst  = (const int*)d_in[2];

  const float* W[5][4];
  for (int p = 0; p < 5; ++p)
    for (int q = 0; q < 4; ++q)
      W[p][q] = (const float*)d_in[3 + p * 4 + q];

  // workspace: st(f32) + 4x fp8 M arrays + CSR + packed weights
  float* st = (float*)d_ws;                          // [N,D] f32
  u8* Mp_f = (u8*)(st + (size_t)Nn * Dd);            // ping fwd [N,D] fp8
  u8* Mp_b = Mp_f + (size_t)Nn * Dd;                 // ping bwd
  u8* Mq_f = Mp_b + (size_t)Nn * Dd;                 // pong fwd
  u8* Mq_b = Mq_f + (size_t)Nn * Dd;                 // pong bwd
  int* ip       = (int*)(Mq_b + (size_t)Nn * Dd);
  int* rp_f     = ip;                 ip += Nn + 1;  // rp_b contiguous after
  int* rp_b     = ip;                 ip += Nn + 1;
  int* col_f    = ip;                 ip += Ee;
  int* col_b    = ip;                 ip += Ee;
  int* bcnt     = ip;                 ip += 2 * 256;
  int* bbase    = ip;                 ip += 2 * 257;
  int* bcur     = ip;                 ip += 2 * 256;
  ushort* Wp = (ushort*)(((uintptr_t)ip + 63) & ~(uintptr_t)63);  // 640 KB
  float* out = (float*)d_out;                        // [N, 2D] f32

  // pairs buffer (6.4 MB) aliases the Mq pong region (12.8 MB): CSR build
  // completes (stream-ordered) before round 1 writes Mq.
  uint* pairs = (uint*)Mq_f;

  const int aggBlocks  = (Nn + TEA - 1) / TEA;    // 1563 tiles
  const int dualBlocks = 2 * aggBlocks;           // 3126
  const int nScatter   = 2 * SB;                  // 782

  WPtrs wpk;  // slots: 2p = W[p].w1, 2p+1 = W[p].w2
  for (int p = 0; p < 5; ++p) { wpk.w[2 * p] = W[p][0]; wpk.w[2 * p + 1] = W[p][2]; }

  #define WS(m) (Wp + (size_t)(m) * WSLOT)
  // fwd: upd = fu (p=2), msg = fp (p=1); bwd: upd = bu (p=4), msg = bp (p=3)
  DirP Pf = { WS(4), WS(5), WS(2), WS(3), W[2][1], W[2][3], W[1][1], W[1][3] };
  DirP Pb = { WS(8), WS(9), WS(6), WS(7), W[4][1], W[4][3], W[3][1], W[3][3] };

  // ---- CSR build + fused scatter/stmsg ----
  hipMemsetAsync(bcnt, 0, 2 * 256 * sizeof(int), stream);
  csr_count<<<dim3(SB, 2), 256, 0, stream>>>(src, dst, bcnt);
  csr_scan_pack<<<641, 256, 0, stream>>>(bcnt, bbase, bcur, rp_f, wpk, Wp);
  scatter_stmsg_kernel<<<nScatter + aggBlocks, NT, 0, stream>>>(
      src, dst, bcur, pairs, feat, WS(0), WS(1), W[0][1], W[0][3],
      Pf, Pb, st, Mp_f, Mp_b, nScatter);
  csr_final<<<dim3(NBUK, 2), 256, 0, stream>>>(pairs, bbase, rp_f, col_f, col_b);

  // ---- round 1: agg+upd+msg, ping -> pong ----
  aggupdmsg_kernel<1><<<dualBlocks, NT, 0, stream>>>(
      Mp_f, Mp_b, rp_f, rp_b, col_f, col_b, st,
      Mq_f, Mq_b, nullptr, nullptr, 0, Pf, Pb, aggBlocks);

  // ---- round 2: agg+upd+msg, pong -> ping ----
  aggupdmsg_kernel<1><<<dualBlocks, NT, 0, stream>>>(
      Mq_f, Mq_b, rp_f, rp_b, col_f, col_b, st,
      Mp_f, Mp_b, nullptr, nullptr, 0, Pf, Pb, aggBlocks);

  // ---- round 3 (final): agg+upd, ping -> y into out column-halves ----
  aggupdmsg_kernel<0><<<dualBlocks, NT, 0, stream>>>(
      Mp_f, Mp_b, rp_f, rp_b, col_f, col_b, st,
      nullptr, nullptr, out, out + Dd, 2 * Dd, Pf, Pb, aggBlocks);

  #undef WS
}

// Round 16
// 487.612 us; speedup vs baseline: 1.1620x; 1.0010x over previous
//
#include <hip/hip_runtime.h>

// Problem constants (reference: N=50000 nodes, E=800000 edges, D=128, K=3)
#define Nn 50000
#define Ee 800000
#define Dd 128
#define Kk 3
#define TEA 32   // rows per block tile (17.4 KB LDS)
#define NT 256   // threads per block (4 waves)

// LDS bf16 tile row stride (ushorts): 128 + 8 pad
#define LSTR 136
// Per-matrix packed-weight slot: hi[16384] + lo[16384] ushorts
#define WSLOT 32768

// Bucket sort CSR build: bucket = node >> 8 (196 buckets for N=50000)
#define NBUK 196
#define SCH 2048                      // edges per sort block
#define SB ((Ee + SCH - 1) / SCH)     // 391 blocks per direction
#define FCAP 5632                     // csr_final LDS staging capacity

typedef short sh8 __attribute__((ext_vector_type(8)));    // 8 bf16 (4 VGPRs)
typedef float f32x4 __attribute__((ext_vector_type(4)));  // MFMA C/D
typedef unsigned char u8;

// Split fp32 into bf16 hi (truncate) + bf16 lo (residual, truncate).
__device__ __forceinline__ ushort bfsplit(float x, float* rem) {
  const unsigned u = __float_as_uint(x);
  *rem = x - __uint_as_float(u & 0xffff0000u);
  return (ushort)(u >> 16);
}
__device__ __forceinline__ ushort bftrunc(float x) {
  return (ushort)(__float_as_uint(x) >> 16);
}

// ---- fp8 OCP e4m3fn (software, self-consistent pair; x >= 0 after relu) ----
// encode: RNE at 3-bit mantissa; denormals via round(x*512); clip to 448.
__device__ __forceinline__ u8 f32_to_e4m3(float x) {
  x = fminf(x, 448.f);
  if (x < 0.015625f) return (u8)__float2int_rn(x * 512.f);   // denorm/zero
  const unsigned u = __float_as_uint(x);
  const unsigned r = u + 0x7FFFFu + ((u >> 20) & 1u);        // RNE carry-safe
  const unsigned e = (r >> 23) - 120u;                       // 1..15
  return (u8)((e << 3) | ((r >> 20) & 7u));
}
// decode (branch-free, bit-exact for ALL codes incl. denorm/zero):
// as_float(b<<20) * 2^120.  Normals: +120 on exponent == the bias trick.
// Denorm b<8: f32-denorm b*2^-129 scaled by 2^120 = b*2^-9 exactly.
#define E4M3_SCALE 1.329227995784916e+36f  /* 0x1p120 */
// accumulate 4 fp8 bytes packed in a uint into a float4 (3 VALU ops/byte)
__device__ __forceinline__ void accq(unsigned u, float4& a) {
  a.x = fmaf(__uint_as_float((u & 0x000000FFu) << 20), E4M3_SCALE, a.x);
  a.y = fmaf(__uint_as_float((u & 0x0000FF00u) << 12), E4M3_SCALE, a.y);
  a.z = fmaf(__uint_as_float((u & 0x00FF0000u) << 4),  E4M3_SCALE, a.z);
  a.w = fmaf(__uint_as_float((u >> 4) & 0x0FF00000u),  E4M3_SCALE, a.w);
}
#define DEC16(v, za) { accq((v).x, za[0]); accq((v).y, za[1]); \
                       accq((v).z, za[2]); accq((v).w, za[3]); }

// (MT*16)x128x128 layer on MFMA 16x16x32_bf16, split-bf16 (3 products).
#define MFMA_LAYER(WH, WL, MT)                                                 \
  {                                                                            \
    _Pragma("unroll")                                                          \
    for (int c = 0; c < 4; ++c) {                                              \
      const sh8 bh0 = *(const sh8*)((WH) + (((nt0    ) * 4 + c) * 64 + lane) * 8); \
      const sh8 bh1 = *(const sh8*)((WH) + (((nt0 + 1) * 4 + c) * 64 + lane) * 8); \
      const sh8 bl0 = *(const sh8*)((WL) + (((nt0    ) * 4 + c) * 64 + lane) * 8); \
      const sh8 bl1 = *(const sh8*)((WL) + (((nt0 + 1) * 4 + c) * 64 + lane) * 8); \
      _Pragma("unroll")                                                        \
      for (int mt = 0; mt < (MT); ++mt) {                                      \
        const int aoff = (mt * 16 + l15) * LSTR + c * 32 + q8 * 8;             \
        const sh8 ah = *(const sh8*)(Sh + aoff);                               \
        const sh8 al = *(const sh8*)(Sl + aoff);                               \
        acc[mt][0] = __builtin_amdgcn_mfma_f32_16x16x32_bf16(ah, bh0, acc[mt][0], 0, 0, 0); \
        acc[mt][1] = __builtin_amdgcn_mfma_f32_16x16x32_bf16(ah, bh1, acc[mt][1], 0, 0, 0); \
        acc[mt][0] = __builtin_amdgcn_mfma_f32_16x16x32_bf16(al, bh0, acc[mt][0], 0, 0, 0); \
        acc[mt][1] = __builtin_amdgcn_mfma_f32_16x16x32_bf16(al, bh1, acc[mt][1], 0, 0, 0); \
        acc[mt][0] = __builtin_amdgcn_mfma_f32_16x16x32_bf16(ah, bl0, acc[mt][0], 0, 0, 0); \
        acc[mt][1] = __builtin_amdgcn_mfma_f32_16x16x32_bf16(ah, bl1, acc[mt][1], 0, 0, 0); \
      }                                                                        \
    }                                                                          \
  }

#define ZERO_ACC(MT)                                             \
  {                                                              \
    _Pragma("unroll")                                            \
    for (int mt = 0; mt < (MT); ++mt)                            \
      _Pragma("unroll")                                          \
      for (int nl = 0; nl < 2; ++nl) {                           \
        acc[mt][nl][0] = 0.f; acc[mt][nl][1] = 0.f;              \
        acc[mt][nl][2] = 0.f; acc[mt][nl][3] = 0.f;              \
      }                                                          \
  }

// hidden = relu(acc + b1) -> split hi/lo back into LDS (C layout -> A layout)
#define HIDDEN_TO_LDS(B1ptr, MT)                                 \
  {                                                              \
    const float b1a = (B1ptr)[w32 + l15];                        \
    const float b1b = (B1ptr)[w32 + 16 + l15];                   \
    _Pragma("unroll")                                            \
    for (int mt = 0; mt < (MT); ++mt)                            \
      _Pragma("unroll")                                          \
      for (int nl = 0; nl < 2; ++nl) {                           \
        const int col = w32 + nl * 16 + l15;                     \
        const float bb = nl ? b1b : b1a;                         \
        _Pragma("unroll")                                        \
        for (int rg = 0; rg < 4; ++rg) {                         \
          const int row = mt * 16 + q8 * 4 + rg;                 \
          const float h = fmaxf(acc[mt][nl][rg] + bb, 0.f);      \
          float rm;                                              \
          const ushort hh = bfsplit(h, &rm);                     \
          const int off = row * LSTR + col;                      \
          Sh[off] = hh;                                          \
          Sl[off] = bftrunc(rm);                                 \
        }                                                        \
      }                                                          \
  }

// stc (C-layout f32, bias included, signed) -> split into LDS A-layout
#define STC_TO_LDS(MT)                                           \
  {                                                              \
    _Pragma("unroll")                                            \
    for (int mt = 0; mt < (MT); ++mt)                            \
      _Pragma("unroll")                                          \
      for (int nl = 0; nl < 2; ++nl) {                           \
        const int col = w32 + nl * 16 + l15;                     \
        _Pragma("unroll")                                        \
        for (int rg = 0; rg < 4; ++rg) {                         \
          const int row = mt * 16 + q8 * 4 + rg;                 \
          float rm;                                              \
          const ushort hh = bfsplit(stc[mt][nl][rg], &rm);       \
          const int off = row * LSTR + col;                      \
          Sh[off] = hh;                                          \
          Sl[off] = bftrunc(rm);                                 \
        }                                                        \
      }                                                          \
  }

// stage rows [row0, row0+nrow) of row-major f32 X (stride Dd) into Sh/Sl split
#define STAGE_ROWS(Xptr)                                                       \
  {                                                                            \
    _Pragma("unroll")                                                          \
    for (int it = 0; it < (TEA * 32 / NT); ++it) {                             \
      const int i = t + NT * it;                                               \
      const int r = i >> 5;                                                    \
      const int c4 = (i & 31) << 2;                                            \
      float4 v = make_float4(0.f, 0.f, 0.f, 0.f);                              \
      if (r < nrow) v = *(const float4*)((Xptr) + (size_t)(row0 + r) * Dd + c4); \
      ushort4 hv, lv; float rm;                                                \
      hv.x = bfsplit(v.x, &rm); lv.x = bftrunc(rm);                            \
      hv.y = bfsplit(v.y, &rm); lv.y = bftrunc(rm);                            \
      hv.z = bfsplit(v.z, &rm); lv.z = bftrunc(rm);                            \
      hv.w = bfsplit(v.w, &rm); lv.w = bftrunc(rm);                            \
      *(ushort4*)(&Sh[r * LSTR + c4]) = hv;                                    \
      *(ushort4*)(&Sl[r * LSTR + c4]) = lv;                                    \
    }                                                                          \
  }

#define MFMA_PRELUDE(MT)                                         \
  const int lane = t & 63;                                       \
  const int wave = t >> 6;                                       \
  const int l15 = lane & 15;                                     \
  const int q8 = lane >> 4;                                      \
  const int w32 = wave * 32;                                     \
  const int nt0 = wave * 2;                                      \
  f32x4 acc[MT][2];

// Per-direction parameter pack: packed hi bases (lo = +16384) + biases.
struct DirP {
  const ushort *u1, *u2, *p1, *p2;             // upd w1/w2, msg w1/w2 (packed)
  const float *ub1, *ub2, *pb1, *pb2;
};

struct WPtrs { const float* w[10]; };

// ---------------------------------------------------------------------------
// CSR build via 2-level bucket sort (bucket = node >> 8, 196 buckets).
// pairs[dir][i] = (key << 16) | val  (both < 65536 since N = 50000).
// ---------------------------------------------------------------------------
__global__ __launch_bounds__(256) void csr_count(
    const int* __restrict__ src, const int* __restrict__ dst,
    int* __restrict__ bcnt)
{
  const int dirv = blockIdx.y;
  const int* key = dirv ? src : dst;
  __shared__ int h[NBUK];
  const int t = threadIdx.x;
  if (t < NBUK) h[t] = 0;
  __syncthreads();
  const int e0 = blockIdx.x * SCH;
  #pragma unroll
  for (int i = 0; i < SCH / 256; ++i) {
    const int e = e0 + i * 256 + t;
    if (e < Ee) atomicAdd(&h[key[e] >> 8], 1);
  }
  __syncthreads();
  if (t < NBUK && h[t] > 0) atomicAdd(&bcnt[dirv * 256 + t], h[t]);
}

// block 0: bucket scan; blocks 1..640: weight packing (independent work,
// fused to hide the serial scan behind the pack kernel's runtime).
__global__ __launch_bounds__(256) void csr_scan_pack(
    const int* __restrict__ bcnt, int* __restrict__ bbase,
    int* __restrict__ bcur, int* __restrict__ rp,
    WPtrs P, ushort* __restrict__ out)
{
  const int t = threadIdx.x;
  if (blockIdx.x == 0) {
    __shared__ int s[256];
    for (int y = 0; y < 2; ++y) {
      const int v = (t < NBUK) ? bcnt[y * 256 + t] : 0;
      s[t] = v;
      __syncthreads();
      for (int off = 1; off < 256; off <<= 1) {
        int x = s[t];
        if (t >= off) x += s[t - off];
        __syncthreads();
        s[t] = x;
        __syncthreads();
      }
      const int excl = s[t] - v;
      if (t < NBUK) { bbase[y * 257 + t] = excl; bcur[y * 256 + t] = excl; }
      if (t == NBUK - 1) bbase[y * 257 + NBUK] = s[t];
      if (t == 0) rp[y * (Nn + 1) + Nn] = Ee;
      __syncthreads();
    }
  } else {
    const int work = (blockIdx.x - 1) * 256 + t;  // 0..163839
    const int mat = work >> 14;                   // /16384
    const int id = work & 16383;
    const int j = id & 7;
    const int lane = (id >> 3) & 63;
    const int ch = (id >> 9) & 3;
    const int nt = id >> 11;
    const int k = ch * 32 + (lane >> 4) * 8 + j;
    const int n = nt * 16 + (lane & 15);
    const float x = P.w[mat][k * Dd + n];
    float rm;
    const ushort h = bfsplit(x, &rm);
    out[(size_t)mat * WSLOT + id] = h;
    out[(size_t)mat * WSLOT + 16384 + id] = bftrunc(rm);
  }
}

// ---------------------------------------------------------------------------
// Fused kernel: blocks [0, 2*SB) = CSR scatter (compact append at pre-scanned
// bases); blocks [2*SB, ...) = stmsg. Messages stored as fp8 e4m3fn.
// ---------------------------------------------------------------------------
__global__ __launch_bounds__(NT) void scatter_stmsg_kernel(
    const int* __restrict__ src, const int* __restrict__ dst,
    int* __restrict__ bcur, uint* __restrict__ pairs,
    const float* __restrict__ X,
    const ushort* __restrict__ Wn1, const ushort* __restrict__ Wn2,
    const float* __restrict__ Bn1, const float* __restrict__ Bn2,
    DirP pf, DirP pb,
    float* __restrict__ st, u8* __restrict__ Mf, u8* __restrict__ Mb,
    int nScatter)
{
  __shared__ __align__(16) ushort Sbuf[2 * TEA * LSTR];  // 17.4 KB
  const int t = threadIdx.x;

  if ((int)blockIdx.x < nScatter) {
    // ---- scatter branch (R12-verified body) ----
    int* lh = (int*)Sbuf;
    int* gb = lh + 256;
    int* lc = gb + 256;
    const int dirv = (int)blockIdx.x >= SB;
    const int sb = blockIdx.x - dirv * SB;
    const int* key = dirv ? src : dst;
    const int* val = dirv ? dst : src;
    if (t < NBUK) { lh[t] = 0; lc[t] = 0; }
    __syncthreads();
    const int e0 = sb * SCH;
    int ks[SCH / 256], vs[SCH / 256];
    #pragma unroll
    for (int i = 0; i < SCH / 256; ++i) {
      const int e = e0 + i * 256 + t;
      ks[i] = (e < Ee) ? key[e] : -1;
      vs[i] = (e < Ee) ? val[e] : 0;
      if (ks[i] >= 0) atomicAdd(&lh[ks[i] >> 8], 1);
    }
    __syncthreads();
    if (t < NBUK && lh[t] > 0) gb[t] = atomicAdd(&bcur[dirv * 256 + t], lh[t]);
    __syncthreads();
    uint* pd = pairs + (size_t)dirv * Ee;
    #pragma unroll
    for (int i = 0; i < SCH / 256; ++i) {
      if (ks[i] >= 0) {
        const int b = ks[i] >> 8;
        const int r = atomicAdd(&lc[b], 1);
        pd[gb[b] + r] = ((uint)ks[i] << 16) | (uint)vs[i];
      }
    }
    return;
  }

  // ---- stmsg branch ----
  ushort* Sh = Sbuf;
  ushort* Sl = Sbuf + TEA * LSTR;
  const int bid = blockIdx.x - nScatter;
  const int row0 = bid * TEA;
  const int rem = Nn - row0;
  const int nrow = rem < TEA ? rem : TEA;

  STAGE_ROWS(X);
  __syncthreads();
  MFMA_PRELUDE(2);

  // ---- nt MLP -> stc ----
  ZERO_ACC(2);
  MFMA_LAYER(Wn1, Wn1 + 16384, 2);
  __syncthreads();
  HIDDEN_TO_LDS(Bn1, 2);
  __syncthreads();
  ZERO_ACC(2);
  MFMA_LAYER(Wn2, Wn2 + 16384, 2);

  float stc[2][2][4];
  {
    const float b2a = Bn2[w32 + l15];
    const float b2b = Bn2[w32 + 16 + l15];
    #pragma unroll
    for (int mt = 0; mt < 2; ++mt)
      #pragma unroll
      for (int nl = 0; nl < 2; ++nl) {
        const int col = w32 + nl * 16 + l15;
        const float bb = nl ? b2b : b2a;
        #pragma unroll
        for (int rg = 0; rg < 4; ++rg) {
          const int row = mt * 16 + q8 * 4 + rg;
          const float v = acc[mt][nl][rg] + bb;
          stc[mt][nl][rg] = v;
          if (row < nrow) st[(size_t)(row0 + row) * Dd + col] = v;
        }
      }
  }
  __syncthreads();  // hidden tile fully consumed

  // ---- fwd msg MLP on stc ----
  STC_TO_LDS(2);
  __syncthreads();
  ZERO_ACC(2);
  MFMA_LAYER(pf.p1, pf.p1 + 16384, 2);
  __syncthreads();
  HIDDEN_TO_LDS(pf.pb1, 2);
  __syncthreads();
  ZERO_ACC(2);
  MFMA_LAYER(pf.p2, pf.p2 + 16384, 2);
  {
    const float b2a = pf.pb2[w32 + l15];
    const float b2b = pf.pb2[w32 + 16 + l15];
    #pragma unroll
    for (int mt = 0; mt < 2; ++mt)
      #pragma unroll
      for (int nl = 0; nl < 2; ++nl) {
        const int col = w32 + nl * 16 + l15;
        const float bb = nl ? b2b : b2a;
        #pragma unroll
        for (int rg = 0; rg < 4; ++rg) {
          const int row = mt * 16 + q8 * 4 + rg;
          if (row < nrow)
            Mf[(size_t)(row0 + row) * Dd + col] =
                f32_to_e4m3(fmaxf(acc[mt][nl][rg] + bb, 0.f));
        }
      }
  }
  __syncthreads();

  // ---- bwd msg MLP on stc ----
  STC_TO_LDS(2);
  __syncthreads();
  ZERO_ACC(2);
  MFMA_LAYER(pb.p1, pb.p1 + 16384, 2);
  __syncthreads();
  HIDDEN_TO_LDS(pb.pb1, 2);
  __syncthreads();
  ZERO_ACC(2);
  MFMA_LAYER(pb.p2, pb.p2 + 16384, 2);
  {
    const float b2a = pb.pb2[w32 + l15];
    const float b2b = pb.pb2[w32 + 16 + l15];
    #pragma unroll
    for (int mt = 0; mt < 2; ++mt)
      #pragma unroll
      for (int nl = 0; nl < 2; ++nl) {
        const int col = w32 + nl * 16 + l15;
        const float bb = nl ? b2b : b2a;
        #pragma unroll
        for (int rg = 0; rg < 4; ++rg) {
          const int row = mt * 16 + q8 * 4 + rg;
          if (row < nrow)
            Mb[(size_t)(row0 + row) * Dd + col] =
                f32_to_e4m3(fmaxf(acc[mt][nl][rg] + bb, 0.f));
        }
      }
  }
}

// LDS pair staging + 8-band src-ordered emit (band = src>>13).  [R12 exact]
__global__ __launch_bounds__(256) void csr_final(
    const uint* __restrict__ pairs, const int* __restrict__ bbase,
    int* __restrict__ rp, int* __restrict__ col_f, int* __restrict__ col_b)
{
  const int dirv = blockIdx.y;
  const int b = blockIdx.x;
  const int base = bbase[dirv * 257 + b];
  const int cnt = bbase[dirv * 257 + b + 1] - base;
  const uint* pd = pairs + (size_t)dirv * Ee + base;
  int* colo = dirv ? col_b : col_f;
  __shared__ int h[256];
  __shared__ int s[256];
  __shared__ uint pr[FCAP];   // staged pairs (22.5 KB)
  const int t = threadIdx.x;
  h[t] = 0;
  __syncthreads();
  const bool fits = (cnt <= FCAP);
  if (fits) {
    for (int i = t; i < cnt; i += 256) {
      const uint p = pd[i];
      pr[i] = p;
      atomicAdd(&h[(p >> 16) & 255], 1);
    }
  } else {
    for (int i = t; i < cnt; i += 256) atomicAdd(&h[(pd[i] >> 16) & 255], 1);
  }
  __syncthreads();
  const int v = h[t];
  s[t] = v;
  __syncthreads();
  for (int off = 1; off < 256; off <<= 1) {
    int x = s[t];
    if (t >= off) x += s[t - off];
    __syncthreads();
    s[t] = x;
    __syncthreads();
  }
  const int excl = s[t] - v;
  const int node = b * 256 + t;
  if (node < Nn) rp[dirv * (Nn + 1) + node] = base + excl;
  h[t] = excl;  // becomes per-node cursor
  __syncthreads();
  if (fits) {
    for (int band = 0; band < 8; ++band) {
      for (int i = t; i < cnt; i += 256) {
        const uint p = pr[i];
        const int vv = (int)(p & 0xffffu);
        if ((vv >> 13) == band) {
          const int k = (p >> 16) & 255;
          const int r = atomicAdd(&h[k], 1);
          colo[base + r] = vv;
        }
      }
      __syncthreads();
    }
  } else {
    // fallback (statistically unreachable): plain scatter
    for (int i = t; i < cnt; i += 256) {
      const uint p = pd[i];
      const int k = (p >> 16) & 255;
      const int r = atomicAdd(&h[k], 1);
      colo[base + r] = (int)(p & 0xffffu);
    }
  }
}

// ---------------------------------------------------------------------------
// Fused per-round kernel, dual direction (2*1563 blocks, TEA=32 rows).
// Messages fp8 e4m3fn: row = 128 B = 2 cache lines. Phase A: 8 threads per
// node row; thread o8 owns bytes o8*16..+15 (one uint4 load per edge);
// branch-free 3-op/byte decode via as_float(b<<20)*2^120 (bit-exact).
// MLPs: full split-bf16 (R15's single-product downgrade FAILED absmax:
// z averages ~16 fp8 errors so MLP precision still matters).
// ---------------------------------------------------------------------------
template <int DO_MSG>
__global__ __launch_bounds__(NT) void aggupdmsg_kernel(
    const u8* __restrict__ Min_f, const u8* __restrict__ Min_b,
    const int* __restrict__ rp_f, const int* __restrict__ rp_b,
    const int* __restrict__ col_f, const int* __restrict__ col_b,
    const float* __restrict__ st,
    u8* __restrict__ RMf, u8* __restrict__ RMb,
    float* __restrict__ RYf, float* __restrict__ RYb, int rstride,
    DirP pf, DirP pb, int nhalf)
{
  __shared__ __align__(16) ushort Sbuf[2 * TEA * LSTR];  // 17.4 KB
  ushort* Sh = Sbuf;
  ushort* Sl = Sbuf + TEA * LSTR;
  const int t = threadIdx.x;
  const int dir = blockIdx.x >= nhalf;
  const int row0 = (blockIdx.x - dir * nhalf) * TEA;
  const int rem = Nn - row0;
  const int nrow = rem < TEA ? rem : TEA;
  const DirP P = dir ? pb : pf;
  const u8* Min = dir ? Min_b : Min_f;
  const int* rp = dir ? rp_b : rp_f;
  const int* col = dir ? col_b : col_f;
  u8* RoutM = dir ? RMb : RMf;
  float* RoutY = dir ? RYb : RYf;
  const int sink = dir ? 0 : (Nn - 1);

  // ---- phase A: gather-sum of fp8 M rows, f32 accumulate ----
  {
    const int nr = t >> 3;           // tile row, 8 threads per row
    const int o8 = t & 7;            // 16B sub-chunk (cols o8*16..+15)
    float4 za[4];
    #pragma unroll
    for (int i = 0; i < 4; ++i) za[i] = make_float4(0.f, 0.f, 0.f, 0.f);
    if (nr < nrow) {
      const int gnode = row0 + nr;
      int e = rp[gnode];
      const int ee = rp[gnode + 1];
      const u8* Mo = Min + o8 * 16;   // o8*16 bytes into each 128B row
      for (; e + 3 < ee; e += 4) {    // 4 independent 16B loads in flight
        const int c0 = col[e];
        const int c1 = col[e + 1];
        const int c2 = col[e + 2];
        const int c3 = col[e + 3];
        uint4 v0 = *(const uint4*)(Mo + (size_t)c0 * Dd);
        uint4 v1 = *(const uint4*)(Mo + (size_t)c1 * Dd);
        uint4 v2 = *(const uint4*)(Mo + (size_t)c2 * Dd);
        uint4 v3 = *(const uint4*)(Mo + (size_t)c3 * Dd);
        DEC16(v0, za); DEC16(v1, za); DEC16(v2, za); DEC16(v3, za);
      }
      for (; e < ee; ++e) {
        uint4 v = *(const uint4*)(Mo + (size_t)col[e] * Dd);
        DEC16(v, za);
      }
    }
    #pragma unroll
    for (int k = 0; k < 4; ++k) {
      ushort4 hv, lv; float rm;
      hv.x = bfsplit(za[k].x, &rm); lv.x = bftrunc(rm);
      hv.y = bfsplit(za[k].y, &rm); lv.y = bftrunc(rm);
      hv.z = bfsplit(za[k].z, &rm); lv.z = bftrunc(rm);
      hv.w = bfsplit(za[k].w, &rm); lv.w = bftrunc(rm);
      const int c4 = o8 * 16 + k * 4;
      *(ushort4*)(&Sh[nr * LSTR + c4]) = hv;
      *(ushort4*)(&Sl[nr * LSTR + c4]) = lv;
    }
  }
  __syncthreads();

  MFMA_PRELUDE(2);

  // ---- phase B: update MLP ----
  ZERO_ACC(2);
  MFMA_LAYER(P.u1, P.u1 + 16384, 2);
  __syncthreads();
  HIDDEN_TO_LDS(P.ub1, 2);
  __syncthreads();
  ZERO_ACC(2);
  MFMA_LAYER(P.u2, P.u2 + 16384, 2);

  // y = st + relu(acc + ub2), y[sink-row contribution] zeroed
  {
    const float b2a = P.ub2[w32 + l15];
    const float b2b = P.ub2[w32 + 16 + l15];
    if (DO_MSG) __syncthreads();  // all hidden reads done before overwrite
    #pragma unroll
    for (int mt = 0; mt < 2; ++mt)
      #pragma unroll
      for (int nl = 0; nl < 2; ++nl) {
        const int col = w32 + nl * 16 + l15;
        const float bb = nl ? b2b : b2a;
        #pragma unroll
        for (int rg = 0; rg < 4; ++rg) {
          const int row = mt * 16 + q8 * 4 + rg;
          float v = 0.f;
          if (row < nrow) {
            const int gr = row0 + row;
            v = fmaxf(acc[mt][nl][rg] + bb, 0.f);
            if (gr == sink) v = 0.f;
            v += st[(size_t)gr * Dd + col];
          }
          if (DO_MSG) {
            float rm;
            const ushort hh = bfsplit(v, &rm);
            const int off = row * LSTR + col;
            Sh[off] = hh;
            Sl[off] = bftrunc(rm);
          } else if (row < nrow) {
            RoutY[(size_t)(row0 + row) * rstride + col] = v;
          }
        }
      }
  }

  if (DO_MSG) {
    __syncthreads();
    // ---- phase C: msg MLP on y-tile ----
    ZERO_ACC(2);
    MFMA_LAYER(P.p1, P.p1 + 16384, 2);
    __syncthreads();
    HIDDEN_TO_LDS(P.pb1, 2);
    __syncthreads();
    ZERO_ACC(2);
    MFMA_LAYER(P.p2, P.p2 + 16384, 2);

    const float b2a = P.pb2[w32 + l15];
    const float b2b = P.pb2[w32 + 16 + l15];
    #pragma unroll
    for (int mt = 0; mt < 2; ++mt)
      #pragma unroll
      for (int nl = 0; nl < 2; ++nl) {
        const int col = w32 + nl * 16 + l15;
        const float bb = nl ? b2b : b2a;
        #pragma unroll
        for (int rg = 0; rg < 4; ++rg) {
          const int row = mt * 16 + q8 * 4 + rg;
          if (row < nrow)
            RoutM[(size_t)(row0 + row) * Dd + col] =
                f32_to_e4m3(fmaxf(acc[mt][nl][rg] + bb, 0.f));
        }
      }
  }
}

// ---------------------------------------------------------------------------
extern "C" void kernel_launch(void* const* d_in, const int* in_sizes, int n_in,
                              void* d_out, int out_size, void* d_ws, size_t ws_size,
                              hipStream_t stream)
{
  const float* feat = (const float*)d_in[0];
  const int*   src  = (const int*)d_in[1];
  const int*   dst  = (const int*)d_in[2];

  const float* W[5][4];
  for (int p = 0; p < 5; ++p)
    for (int q = 0; q < 4; ++q)
      W[p][q] = (const float*)d_in[3 + p * 4 + q];

  // workspace: st(f32) + 4x fp8 M arrays + CSR + packed weights
  float* st = (float*)d_ws;                          // [N,D] f32
  u8* Mp_f = (u8*)(st + (size_t)Nn * Dd);            // ping fwd [N,D] fp8
  u8* Mp_b = Mp_f + (size_t)Nn * Dd;                 // ping bwd
  u8* Mq_f = Mp_b + (size_t)Nn * Dd;                 // pong fwd
  u8* Mq_b = Mq_f + (size_t)Nn * Dd;                 // pong bwd
  int* ip       = (int*)(Mq_b + (size_t)Nn * Dd);
  int* rp_f     = ip;                 ip += Nn + 1;  // rp_b contiguous after
  int* rp_b     = ip;                 ip += Nn + 1;
  int* col_f    = ip;                 ip += Ee;
  int* col_b    = ip;                 ip += Ee;
  int* bcnt     = ip;                 ip += 2 * 256;
  int* bbase    = ip;                 ip += 2 * 257;
  int* bcur     = ip;                 ip += 2 * 256;
  ushort* Wp = (ushort*)(((uintptr_t)ip + 63) & ~(uintptr_t)63);  // 640 KB
  float* out = (float*)d_out;                        // [N, 2D] f32

  // pairs buffer (6.4 MB) aliases the Mq pong region (12.8 MB): CSR build
  // completes (stream-ordered) before round 1 writes Mq.
  uint* pairs = (uint*)Mq_f;

  const int aggBlocks  = (Nn + TEA - 1) / TEA;    // 1563 tiles
  const int dualBlocks = 2 * aggBlocks;           // 3126
  const int nScatter   = 2 * SB;                  // 782

  WPtrs wpk;  // slots: 2p = W[p].w1, 2p+1 = W[p].w2
  for (int p = 0; p < 5; ++p) { wpk.w[2 * p] = W[p][0]; wpk.w[2 * p + 1] = W[p][2]; }

  #define WS(m) (Wp + (size_t)(m) * WSLOT)
  // fwd: upd = fu (p=2), msg = fp (p=1); bwd: upd = bu (p=4), msg = bp (p=3)
  DirP Pf = { WS(4), WS(5), WS(2), WS(3), W[2][1], W[2][3], W[1][1], W[1][3] };
  DirP Pb = { WS(8), WS(9), WS(6), WS(7), W[4][1], W[4][3], W[3][1], W[3][3] };

  // ---- CSR build + fused scatter/stmsg ----
  hipMemsetAsync(bcnt, 0, 2 * 256 * sizeof(int), stream);
  csr_count<<<dim3(SB, 2), 256, 0, stream>>>(src, dst, bcnt);
  csr_scan_pack<<<641, 256, 0, stream>>>(bcnt, bbase, bcur, rp_f, wpk, Wp);
  scatter_stmsg_kernel<<<nScatter + aggBlocks, NT, 0, stream>>>(
      src, dst, bcur, pairs, feat, WS(0), WS(1), W[0][1], W[0][3],
      Pf, Pb, st, Mp_f, Mp_b, nScatter);
  csr_final<<<dim3(NBUK, 2), 256, 0, stream>>>(pairs, bbase, rp_f, col_f, col_b);

  // ---- round 1: agg+upd+msg, ping -> pong ----
  aggupdmsg_kernel<1><<<dualBlocks, NT, 0, stream>>>(
      Mp_f, Mp_b, rp_f, rp_b, col_f, col_b, st,
      Mq_f, Mq_b, nullptr, nullptr, 0, Pf, Pb, aggBlocks);

  // ---- round 2: agg+upd+msg, pong -> ping ----
  aggupdmsg_kernel<1><<<dualBlocks, NT, 0, stream>>>(
      Mq_f, Mq_b, rp_f, rp_b, col_f, col_b, st,
      Mp_f, Mp_b, nullptr, nullptr, 0, Pf, Pb, aggBlocks);

  // ---- round 3 (final): agg+upd, ping -> y into out column-halves ----
  aggupdmsg_kernel<0><<<dualBlocks, NT, 0, stream>>>(
      Mp_f, Mp_b, rp_f, rp_b, col_f, col_b, st,
      nullptr, nullptr, out, out + Dd, 2 * Dd, Pf, Pb, aggBlocks);

  #undef WS
}